// Round 14
// baseline (363.867 us; speedup 1.0000x reference)
//
#include <hip/hip_runtime.h>
#include <hip/hip_bf16.h>
#include <math.h>

#define NN 200000
#define NE 200000

typedef __attribute__((ext_vector_type(8))) short bf16x8;
typedef __attribute__((ext_vector_type(4))) float f32x4;

#define XASTR 136   // XA row stride (u16): 128 used
#define XBSTR 296   // XB/PB row stride (u16): other(128)|ef(128)|te(16)|zero(16)|pad(8)
#define NT    (NN / 32)            // 6250 tiles, exact
#define PBT   (32 * XBSTR)         // 9472 u16 = 18944 B per tile

__device__ __forceinline__ float sigm(float x) { return 1.0f / (1.0f + __expf(-x)); }
__device__ __forceinline__ float tanh_f(float x) {
    float e = __expf(2.0f * x);
    return 1.0f - 2.0f / (e + 1.0f);
}
__device__ __forceinline__ ushort f2b(float x) {
    union { __hip_bfloat16 b; ushort u; } v;
    v.b = __float2bfloat16(x);
    return v.u;
}
__device__ __forceinline__ float b2f(ushort u) {
    return __uint_as_float(((unsigned)u) << 16);
}
__device__ __forceinline__ ushort4 cvt4(float4 v) {
    ushort4 u; u.x = f2b(v.x); u.y = f2b(v.y); u.z = f2b(v.z); u.w = f2b(v.w);
    return u;
}
__device__ __forceinline__ void gload_lds16(const ushort* g, ushort* l) {
    __builtin_amdgcn_global_load_lds(
        (const __attribute__((address_space(1))) unsigned int*)g,
        (__attribute__((address_space(3))) unsigned int*)l, 16, 0, 0);
}

#define MFMA16(a, b, c) __builtin_amdgcn_mfma_f32_16x16x32_bf16((a), (b), (c), 0, 0, 0)

// ======== K1: last_pos via atomicMax (== segment_max of positions) ========
__global__ void k_scatter(const int* __restrict__ src, const int* __restrict__ dst,
                          int* __restrict__ last_pos) {
    int i = blockIdx.x * blockDim.x + threadIdx.x;
    if (i < NE) {
        atomicMax(&last_pos[src[i]], i);
    } else if (i < 2 * NE) {
        atomicMax(&last_pos[dst[i - NE]], i);
    }
}

// ======== K2: weight prep (blocks 0..NB_PREP-1) || gather (rest) ========
#define NB_PREP 594                     // ceil((104*512 + 2*96*512 + 384)/256)
#define NB_GATH (NN / 16)               // 4 waves x 4 nodes per block
__global__ __launch_bounds__(256)
void k_pg(const float* __restrict__ W1, const float* __restrict__ W2,
          const float* __restrict__ Wih, const float* __restrict__ Whh,
          const float* __restrict__ b2, const float* __restrict__ bih,
          ushort* __restrict__ W1F, ushort* __restrict__ W2IF,
          ushort* __restrict__ WHF, float* __restrict__ cb,
          const int* __restrict__ last_pos,
          const int* __restrict__ src, const int* __restrict__ dst,
          const float* __restrict__ ts, const float* __restrict__ lut,
          const float* __restrict__ mem, const float* __restrict__ ef,
          const float* __restrict__ tw, const float* __restrict__ tphi,
          ushort* __restrict__ PB)
{
    int b = blockIdx.x;
    if (b < NB_PREP) {
        int t = b * 256 + threadIdx.x;
        if (t < 104 * 512) {
            int f = t >> 9, idx = t & 511;
            int lane = idx >> 3, j = idx & 7, c16 = lane & 15, k8 = lane >> 4;
            int wvv = f / 26, r = f % 26, kt = r >> 1, ns = r & 1;
            int col = wvv * 32 + ns * 16 + c16;
            int kk = kt * 32 + k8 * 8 + j;
            W1F[t] = (kk < 400) ? f2b(W1[kk * 128 + col]) : (ushort)0;
            return;
        }
        t -= 104 * 512;
        if (t < 96 * 512) {
            int f = t >> 9, idx = t & 511;
            int lane = idx >> 3, j = idx & 7, c16 = lane & 15, k8 = lane >> 4;
            int wvv = f / 24, r = f % 24, kt = r / 6, rem = r % 6, g = rem >> 1, ns = rem & 1;
            int col = g * 128 + wvv * 32 + ns * 16 + c16;
            int kk = kt * 32 + k8 * 8 + j;
            float s = 0.0f;
            for (int c = 0; c < 128; ++c) s = fmaf(W2[kk * 128 + c], Wih[col * 128 + c], s);
            W2IF[f * 512 + idx] = f2b(s);
            return;
        }
        t -= 96 * 512;
        if (t < 96 * 512) {
            int f = t >> 9, idx = t & 511;
            int lane = idx >> 3, j = idx & 7, c16 = lane & 15, k8 = lane >> 4;
            int wvv = f / 24, r = f % 24, kt = r / 6, rem = r % 6, g = rem >> 1, ns = rem & 1;
            int col = g * 128 + wvv * 32 + ns * 16 + c16;
            int kk = kt * 32 + k8 * 8 + j;
            WHF[f * 512 + idx] = f2b(Whh[col * 128 + kk]);
            return;
        }
        t -= 96 * 512;
        if (t < 384) {
            float s = bih[t];
            for (int k = 0; k < 128; ++k) s = fmaf(b2[k], Wih[t * 128 + k], s);
            cb[t] = s;
        }
        return;
    }

    // ---- gather: 4 nodes/wave, all loads issued before any write ----
    const int wv = threadIdx.x >> 6, lane = threadIdx.x & 63;
    const int n0 = (((b - NB_PREP) * 4) + wv) * 4;
    const int l = lane & 31;
    const bool lo = lane < 32;

    int p[4];
    #pragma unroll
    for (int s = 0; s < 4; ++s) p[s] = last_pos[n0 + s];

    float4 mv[4], fv[4];
    float te[4];
    #pragma unroll
    for (int s = 0; s < 4; ++s) {
        te[s] = 0.0f;
        if (p[s] >= 0) {                   // wave-uniform branch
            int e = (p[s] < NE) ? p[s] : p[s] - NE;
            int o = (p[s] < NE) ? dst[e] : src[e];
            if (lo) {
                mv[s] = *(const float4*)&mem[(size_t)o * 128 + l * 4];
                if (l < 16) {
                    float dt = ts[e] - lut[n0 + s];
                    float w = fmaf(dt, tw[l], tphi[l]);
                    te[s] = (l == 0) ? w : __sinf(w);
                }
            } else {
                fv[s] = *(const float4*)&ef[(size_t)e * 128 + l * 4];
            }
        }
    }
    #pragma unroll
    for (int s = 0; s < 4; ++s) {
        if (p[s] >= 0) {
            ushort* xb = PB + (size_t)(n0 + s) * XBSTR;
            if (lo) {
                *(ushort4*)&xb[l * 4] = cvt4(mv[s]);
                xb[256 + l] = (l < 16) ? f2b(te[s]) : (ushort)0;
            } else {
                *(ushort4*)&xb[128 + l * 4] = cvt4(fv[s]);
            }
        }
    }
}

// ======== K3: main — M=32, LDS diet (H in XB ef-region), 5 blocks/CU ========
__global__ __launch_bounds__(256, 5)
void k_main11(const ushort* __restrict__ PB, const int* __restrict__ last_pos,
              const float* __restrict__ mem,
              const ushort* __restrict__ W1F, const float* __restrict__ b1,
              const ushort* __restrict__ W2IF, const ushort* __restrict__ WHF,
              const float* __restrict__ cb, const float* __restrict__ bhh,
              float* __restrict__ out)
{
    __shared__ __align__(16) ushort XA[32 * XASTR];   // mem[n] bf16
    __shared__ __align__(16) ushort XB[32 * XBSTR];   // staged PB; H overlays ef cols
    __shared__ unsigned char pres[32];

    const int tile = (NT - 1) - blockIdx.x;    // reverse: read freshest PB tiles first
    const int base = tile * 32;
    const int tid  = threadIdx.x;
    const int lane = tid & 63;
    const int wv   = tid >> 6;
    const int r16  = lane & 15;
    const int kb   = lane >> 4;

    // ---- S1: PB tile -> XB via direct global->LDS (18 x 1KB + 1 x 512B) ----
    {
        const ushort* srcPB = PB + (size_t)tile * PBT;
        #pragma unroll
        for (int j = 0; j < 5; ++j) {
            int cc = wv + j * 4;
            if (cc < 18) gload_lds16(srcPB + cc * 512 + lane * 8, XB + cc * 512);
            else if (cc == 18 && lane < 32) gload_lds16(srcPB + cc * 512 + lane * 8, XB + cc * 512);
        }
    }
    // ---- S2: mem rows (sequential, coalesced) -> bf16 -> XA; presence flags ----
    {
        const float* msrc = mem + (size_t)base * 128;
        #pragma unroll
        for (int k = 0; k < 4; ++k) {
            int i0 = k * 1024 + tid * 4;
            float4 v = *(const float4*)&msrc[i0];
            *(ushort4*)&XA[(i0 >> 7) * XASTR + (i0 & 127)] = cvt4(v);
        }
        if (tid < 32) pres[tid] = (unsigned char)(last_pos[base + tid] >= 0);
    }
    const ushort* w1 = W1F  + wv * (26 * 512) + lane * 8;
    const ushort* wI = W2IF + wv * (24 * 512) + lane * 8;
    const ushort* wH = WHF  + wv * (24 * 512) + lane * 8;
    __syncthreads();                       // bar1: staging visible

    // ---- C1: layer 1  h1 = relu(x @ W1 + b1), depth-4 B prefetch ----
    f32x4 c1[2][2] = {};
    {
        const ushort* aA = &XA[r16 * XASTR + kb * 8];
        const ushort* aB = &XB[r16 * XBSTR + kb * 8];
        bf16x8 p0[4], p1[4];
        #pragma unroll
        for (int q = 0; q < 4; ++q) {
            p0[q] = *(const bf16x8*)(w1 + (q * 2 + 0) * 512);
            p1[q] = *(const bf16x8*)(w1 + (q * 2 + 1) * 512);
        }
        #pragma unroll
        for (int kt = 0; kt < 13; ++kt) {
            const ushort* ap  = (kt < 4) ? (aA + kt * 32) : (aB + (kt - 4) * 32);
            const int     ast = (kt < 4) ? XASTR : XBSTR;
            bf16x8 A0 = *(const bf16x8*)ap;
            bf16x8 A1 = *(const bf16x8*)(ap + 16 * ast);
            bf16x8 B0 = p0[kt & 3];
            bf16x8 B1 = p1[kt & 3];
            c1[0][0] = MFMA16(A0, B0, c1[0][0]);
            c1[0][1] = MFMA16(A0, B1, c1[0][1]);
            c1[1][0] = MFMA16(A1, B0, c1[1][0]);
            c1[1][1] = MFMA16(A1, B1, c1[1][1]);
            if (kt + 4 < 13) {
                p0[kt & 3] = *(const bf16x8*)(w1 + ((kt + 4) * 2 + 0) * 512);
                p1[kt & 3] = *(const bf16x8*)(w1 + ((kt + 4) * 2 + 1) * 512);
            }
        }
    }
    __syncthreads();                       // bar2: all C1 XB reads done

    // ---- H write -> XB ef-region (u16 cols 128..255, dead after C1) ----
    #pragma unroll
    for (int ns = 0; ns < 2; ++ns) {
        int col = wv * 32 + ns * 16 + r16;
        float bb = b1[col];
        #pragma unroll
        for (int m = 0; m < 2; ++m)
            #pragma unroll
            for (int r = 0; r < 4; ++r)
                XB[(m * 16 + kb * 4 + r) * XBSTR + 128 + col] =
                    f2b(fmaxf(c1[m][ns][r] + bb, 0.0f));
    }
    __syncthreads();                       // bar3: H visible

    // ---- C3+C4: GRU ns-split, depth-4 prefetch; direct pres-masked stores ----
    #pragma unroll
    for (int ns = 0; ns < 2; ++ns) {
        f32x4 arz[2][2] = {};   // [m][gate r/z]
        f32x4 an_i[2] = {};
        f32x4 an_h[2] = {};
        const ushort* am = &XB[r16 * XBSTR + 128 + kb * 8];
        const ushort* ah = &XA[r16 * XASTR + kb * 8];
        bf16x8 pi[4], ph[4];
        #pragma unroll
        for (int q = 0; q < 4; ++q) {
            int kt = q / 3, s = q % 3;
            int fo = (kt * 6 + s * 2 + ns) * 512;
            pi[q] = *(const bf16x8*)(wI + fo);
            ph[q] = *(const bf16x8*)(wH + fo);
        }
        #pragma unroll
        for (int q = 0; q < 12; ++q) {
            int kt = q / 3, s = q % 3;
            bf16x8 M0 = *(const bf16x8*)(am + kt * 32);
            bf16x8 M1 = *(const bf16x8*)(am + 16 * XBSTR + kt * 32);
            bf16x8 H0 = *(const bf16x8*)(ah + kt * 32);
            bf16x8 H1 = *(const bf16x8*)(ah + 16 * XASTR + kt * 32);
            bf16x8 Bi = pi[q & 3];
            bf16x8 Bh = ph[q & 3];
            if (s < 2) {
                arz[0][s] = MFMA16(M0, Bi, arz[0][s]);
                arz[0][s] = MFMA16(H0, Bh, arz[0][s]);
                arz[1][s] = MFMA16(M1, Bi, arz[1][s]);
                arz[1][s] = MFMA16(H1, Bh, arz[1][s]);
            } else {
                an_i[0] = MFMA16(M0, Bi, an_i[0]);
                an_i[1] = MFMA16(M1, Bi, an_i[1]);
                an_h[0] = MFMA16(H0, Bh, an_h[0]);
                an_h[1] = MFMA16(H1, Bh, an_h[1]);
            }
            if (q + 4 < 12) {
                int kq = (q + 4) / 3, sq = (q + 4) % 3;
                int fo = (kq * 6 + sq * 2 + ns) * 512;
                pi[q & 3] = *(const bf16x8*)(wI + fo);
                ph[q & 3] = *(const bf16x8*)(wH + fo);
            }
        }
        // C4 for this ns: gates + blend -> direct 64B-piece stores (pres-masked)
        {
            int col = wv * 32 + ns * 16 + r16;
            float brz0 = cb[col] + bhh[col];
            float brz1 = cb[128 + col] + bhh[128 + col];
            float bin  = cb[256 + col];
            float bhn  = bhh[256 + col];
            #pragma unroll
            for (int m = 0; m < 2; ++m) {
                #pragma unroll
                for (int r = 0; r < 4; ++r) {
                    int row = m * 16 + kb * 4 + r;
                    if (pres[row]) {
                        float rr = sigm(arz[m][0][r] + brz0);
                        float zz = sigm(arz[m][1][r] + brz1);
                        float nn = tanh_f(an_i[m][r] + bin + rr * (an_h[m][r] + bhn));
                        float hh = b2f(XA[row * XASTR + col]);
                        out[(size_t)(base + row) * 128 + col] = fmaf(zz, hh - nn, nn);
                    }
                }
            }
        }
    }

    // ---- C5: absent rows = exact f32 copy of mem (no barrier needed) ----
    for (int j = wv; j < 32; j += 4) {
        if (!pres[j]) {
            float2 v = *(const float2*)&mem[(size_t)(base + j) * 128 + lane * 2];
            *(float2*)&out[(size_t)(base + j) * 128 + lane * 2] = v;
        }
    }
}

extern "C" void kernel_launch(void* const* d_in, const int* in_sizes, int n_in,
                              void* d_out, int out_size, void* d_ws, size_t ws_size,
                              hipStream_t stream) {
    const int*   src  = (const int*)d_in[0];
    const int*   dst  = (const int*)d_in[1];
    const float* ef   = (const float*)d_in[2];
    const float* ts   = (const float*)d_in[3];
    const float* mem  = (const float*)d_in[4];
    const float* lut  = (const float*)d_in[5];
    const float* tw   = (const float*)d_in[6];
    const float* tphi = (const float*)d_in[7];
    const float* W1   = (const float*)d_in[8];
    const float* b1   = (const float*)d_in[9];
    const float* W2   = (const float*)d_in[10];
    const float* b2   = (const float*)d_in[11];
    const float* Wih  = (const float*)d_in[12];
    const float* Whh  = (const float*)d_in[13];
    const float* bih  = (const float*)d_in[14];
    const float* bhh  = (const float*)d_in[15];
    float* out = (float*)d_out;

    char* ws = (char*)d_ws;
    size_t off = 0;
    int*    last_pos = (int*)(ws + off);    off += (size_t)NN * 4;
    ushort* W1F      = (ushort*)(ws + off); off += (size_t)104 * 512 * 2;
    ushort* W2IF     = (ushort*)(ws + off); off += (size_t)96 * 512 * 2;
    ushort* WHF      = (ushort*)(ws + off); off += (size_t)96 * 512 * 2;
    float*  cb       = (float*)(ws + off);  off += (size_t)384 * 4 + 64;
    ushort* PB       = (ushort*)(ws + off);   // NN * XBSTR * 2 = 118.4 MB

    hipMemsetAsync(last_pos, 0xFF, (size_t)NN * sizeof(int), stream);  // -1

    k_scatter<<<(2 * NE + 255) / 256, 256, 0, stream>>>(src, dst, last_pos);
    k_pg<<<NB_PREP + NB_GATH, 256, 0, stream>>>(
        W1, W2, Wih, Whh, b2, bih, W1F, W2IF, WHF, cb,
        last_pos, src, dst, ts, lut, mem, ef, tw, tphi, PB);
    k_main11<<<NT, 256, 0, stream>>>(PB, last_pos, mem, W1F, b1, W2IF, WHF, cb, bhh, out);
}

// Round 15
// 229.144 us; speedup vs baseline: 1.5879x; 1.5879x over previous
//
#include <hip/hip_runtime.h>
#include <hip/hip_bf16.h>
#include <math.h>

#define NN 200000
#define NE 200000

typedef __attribute__((ext_vector_type(8))) short bf16x8;
typedef __attribute__((ext_vector_type(4))) float f32x4;

#define XASTR 136   // XA/HB row stride (u16): 128 used
#define XBSTR 296   // XB/PB row stride (u16): other(128)|ef(128)|te(16)|zero(16)|pad(8)
#define OSTR  132   // f32 output-stage row stride (XB reuse)
#define NT    (NN / 32)            // 6250 tiles, exact
#define PBT   (32 * XBSTR)         // 9472 u16 = 18944 B per tile

__device__ __forceinline__ float sigm(float x) { return 1.0f / (1.0f + __expf(-x)); }
__device__ __forceinline__ float tanh_f(float x) {
    float e = __expf(2.0f * x);
    return 1.0f - 2.0f / (e + 1.0f);
}
__device__ __forceinline__ ushort f2b(float x) {
    union { __hip_bfloat16 b; ushort u; } v;
    v.b = __float2bfloat16(x);
    return v.u;
}
__device__ __forceinline__ float b2f(ushort u) {
    return __uint_as_float(((unsigned)u) << 16);
}
__device__ __forceinline__ ushort4 cvt4(float4 v) {
    ushort4 u; u.x = f2b(v.x); u.y = f2b(v.y); u.z = f2b(v.z); u.w = f2b(v.w);
    return u;
}
__device__ __forceinline__ void gload_lds16(const ushort* g, ushort* l) {
    __builtin_amdgcn_global_load_lds(
        (const __attribute__((address_space(1))) unsigned int*)g,
        (__attribute__((address_space(3))) unsigned int*)l, 16, 0, 0);
}

#define MFMA16(a, b, c) __builtin_amdgcn_mfma_f32_16x16x32_bf16((a), (b), (c), 0, 0, 0)

// ======== K1: last_pos via atomicMax (== segment_max of positions) ========
__global__ void k_scatter(const int* __restrict__ src, const int* __restrict__ dst,
                          int* __restrict__ last_pos) {
    int i = blockIdx.x * blockDim.x + threadIdx.x;
    if (i < NE) {
        atomicMax(&last_pos[src[i]], i);
    } else if (i < 2 * NE) {
        atomicMax(&last_pos[dst[i - NE]], i);
    }
}

// ======== K2: weight prep (blocks 0..NB_PREP-1) || gather + absent-copy (rest) ========
#define NB_PREP 594                     // ceil((104*512 + 2*96*512 + 384)/256)
#define NB_GATH (NN / 16)               // 4 waves x 4 nodes per block
__global__ __launch_bounds__(256)
void k_pg(const float* __restrict__ W1, const float* __restrict__ W2,
          const float* __restrict__ Wih, const float* __restrict__ Whh,
          const float* __restrict__ b2, const float* __restrict__ bih,
          ushort* __restrict__ W1F, ushort* __restrict__ W2IF,
          ushort* __restrict__ WHF, float* __restrict__ cb,
          const int* __restrict__ last_pos,
          const int* __restrict__ src, const int* __restrict__ dst,
          const float* __restrict__ ts, const float* __restrict__ lut,
          const float* __restrict__ mem, const float* __restrict__ ef,
          const float* __restrict__ tw, const float* __restrict__ tphi,
          ushort* __restrict__ PB, float* __restrict__ out)
{
    int b = blockIdx.x;
    if (b < NB_PREP) {
        int t = b * 256 + threadIdx.x;
        if (t < 104 * 512) {
            int f = t >> 9, idx = t & 511;
            int lane = idx >> 3, j = idx & 7, c16 = lane & 15, k8 = lane >> 4;
            int wvv = f / 26, r = f % 26, kt = r >> 1, ns = r & 1;
            int col = wvv * 32 + ns * 16 + c16;
            int kk = kt * 32 + k8 * 8 + j;
            W1F[t] = (kk < 400) ? f2b(W1[kk * 128 + col]) : (ushort)0;
            return;
        }
        t -= 104 * 512;
        if (t < 96 * 512) {
            int f = t >> 9, idx = t & 511;
            int lane = idx >> 3, j = idx & 7, c16 = lane & 15, k8 = lane >> 4;
            int wvv = f / 24, r = f % 24, kt = r / 6, rem = r % 6, g = rem >> 1, ns = rem & 1;
            int col = g * 128 + wvv * 32 + ns * 16 + c16;
            int kk = kt * 32 + k8 * 8 + j;
            float s = 0.0f;
            for (int c = 0; c < 128; ++c) s = fmaf(W2[kk * 128 + c], Wih[col * 128 + c], s);
            W2IF[f * 512 + idx] = f2b(s);
            return;
        }
        t -= 96 * 512;
        if (t < 96 * 512) {
            int f = t >> 9, idx = t & 511;
            int lane = idx >> 3, j = idx & 7, c16 = lane & 15, k8 = lane >> 4;
            int wvv = f / 24, r = f % 24, kt = r / 6, rem = r % 6, g = rem >> 1, ns = rem & 1;
            int col = g * 128 + wvv * 32 + ns * 16 + c16;
            int kk = kt * 32 + k8 * 8 + j;
            WHF[f * 512 + idx] = f2b(Whh[col * 128 + kk]);
            return;
        }
        t -= 96 * 512;
        if (t < 384) {
            float s = bih[t];
            for (int k = 0; k < 128; ++k) s = fmaf(b2[k], Wih[t * 128 + k], s);
            cb[t] = s;
        }
        return;
    }

    // ---- gather: 4 nodes/wave, all loads issued before any write ----
    const int wv = threadIdx.x >> 6, lane = threadIdx.x & 63;
    const int n0 = (((b - NB_PREP) * 4) + wv) * 4;
    const int l = lane & 31;
    const bool lo = lane < 32;

    int p[4];
    #pragma unroll
    for (int s = 0; s < 4; ++s) p[s] = last_pos[n0 + s];

    float4 mv[4], fv[4];
    float te[4];
    #pragma unroll
    for (int s = 0; s < 4; ++s) {
        te[s] = 0.0f;
        if (p[s] >= 0) {                   // wave-uniform branch
            int e = (p[s] < NE) ? p[s] : p[s] - NE;
            int o = (p[s] < NE) ? dst[e] : src[e];
            if (lo) {
                mv[s] = *(const float4*)&mem[(size_t)o * 128 + l * 4];
                if (l < 16) {
                    float dt = ts[e] - lut[n0 + s];
                    float w = fmaf(dt, tw[l], tphi[l]);
                    te[s] = (l == 0) ? w : __sinf(w);
                }
            } else {
                fv[s] = *(const float4*)&ef[(size_t)e * 128 + l * 4];
            }
        }
    }
    #pragma unroll
    for (int s = 0; s < 4; ++s) {
        if (p[s] >= 0) {
            ushort* xb = PB + (size_t)(n0 + s) * XBSTR;
            if (lo) {
                *(ushort4*)&xb[l * 4] = cvt4(mv[s]);
                xb[256 + l] = (l < 16) ? f2b(te[s]) : (ushort)0;
            } else {
                *(ushort4*)&xb[128 + l * 4] = cvt4(fv[s]);
            }
        } else {
            // absent node: out row = exact f32 copy of mem (coalesced, n consecutive)
            float2 v = *(const float2*)&mem[(size_t)(n0 + s) * 128 + lane * 2];
            *(float2*)&out[(size_t)(n0 + s) * 128 + lane * 2] = v;
        }
    }
}

// ======== K3: main — M=32, 3 barriers, ns-split acc (round-13 proven config) ========
__global__ __launch_bounds__(256, 4)
void k_main10(const ushort* __restrict__ PB, const int* __restrict__ last_pos,
              const float* __restrict__ mem,
              const ushort* __restrict__ W1F, const float* __restrict__ b1,
              const ushort* __restrict__ W2IF, const ushort* __restrict__ WHF,
              const float* __restrict__ cb, const float* __restrict__ bhh,
              float* __restrict__ out)
{
    __shared__ __align__(16) ushort XA[32 * XASTR];   // mem[n] bf16
    __shared__ __align__(16) ushort HB[32 * XASTR];   // h1 bf16
    __shared__ __align__(16) ushort XB[32 * XBSTR];   // staged PB; later f32 out-stage
    __shared__ unsigned char pres[32];

    const int tile = (NT - 1) - blockIdx.x;    // reverse: read freshest PB tiles first
    const int base = tile * 32;
    const int tid  = threadIdx.x;
    const int lane = tid & 63;
    const int wv   = tid >> 6;
    const int r16  = lane & 15;
    const int kb   = lane >> 4;

    // ---- S1: PB tile -> XB via direct global->LDS (18 x 1KB + 1 x 512B) ----
    {
        const ushort* srcPB = PB + (size_t)tile * PBT;
        #pragma unroll
        for (int j = 0; j < 5; ++j) {
            int cc = wv + j * 4;
            if (cc < 18) gload_lds16(srcPB + cc * 512 + lane * 8, XB + cc * 512);
            else if (cc == 18 && lane < 32) gload_lds16(srcPB + cc * 512 + lane * 8, XB + cc * 512);
        }
    }
    // ---- S2: mem rows (sequential, coalesced) -> bf16 -> XA; presence flags ----
    {
        const float* msrc = mem + (size_t)base * 128;
        #pragma unroll
        for (int k = 0; k < 4; ++k) {
            int i0 = k * 1024 + tid * 4;
            float4 v = *(const float4*)&msrc[i0];
            *(ushort4*)&XA[(i0 >> 7) * XASTR + (i0 & 127)] = cvt4(v);
        }
        if (tid < 32) pres[tid] = (unsigned char)(last_pos[base + tid] >= 0);
    }
    const ushort* w1 = W1F  + wv * (26 * 512) + lane * 8;
    const ushort* wI = W2IF + wv * (24 * 512) + lane * 8;
    const ushort* wH = WHF  + wv * (24 * 512) + lane * 8;
    __syncthreads();                       // bar1: staging visible

    // ---- C1: layer 1  h1 = relu(x @ W1 + b1), depth-4 B prefetch ----
    f32x4 c1[2][2] = {};
    {
        const ushort* aA = &XA[r16 * XASTR + kb * 8];
        const ushort* aB = &XB[r16 * XBSTR + kb * 8];
        bf16x8 p0[4], p1[4];
        #pragma unroll
        for (int q = 0; q < 4; ++q) {
            p0[q] = *(const bf16x8*)(w1 + (q * 2 + 0) * 512);
            p1[q] = *(const bf16x8*)(w1 + (q * 2 + 1) * 512);
        }
        #pragma unroll
        for (int kt = 0; kt < 13; ++kt) {
            const ushort* ap  = (kt < 4) ? (aA + kt * 32) : (aB + (kt - 4) * 32);
            const int     ast = (kt < 4) ? XASTR : XBSTR;
            bf16x8 A0 = *(const bf16x8*)ap;
            bf16x8 A1 = *(const bf16x8*)(ap + 16 * ast);
            bf16x8 B0 = p0[kt & 3];
            bf16x8 B1 = p1[kt & 3];
            c1[0][0] = MFMA16(A0, B0, c1[0][0]);
            c1[0][1] = MFMA16(A0, B1, c1[0][1]);
            c1[1][0] = MFMA16(A1, B0, c1[1][0]);
            c1[1][1] = MFMA16(A1, B1, c1[1][1]);
            if (kt + 4 < 13) {
                p0[kt & 3] = *(const bf16x8*)(w1 + ((kt + 4) * 2 + 0) * 512);
                p1[kt & 3] = *(const bf16x8*)(w1 + ((kt + 4) * 2 + 1) * 512);
            }
        }
    }
    // ---- H write -> HB (separate buffer: no barrier needed before) ----
    #pragma unroll
    for (int ns = 0; ns < 2; ++ns) {
        int col = wv * 32 + ns * 16 + r16;
        float bb = b1[col];
        #pragma unroll
        for (int m = 0; m < 2; ++m)
            #pragma unroll
            for (int r = 0; r < 4; ++r)
                HB[(m * 16 + kb * 4 + r) * XASTR + col] =
                    f2b(fmaxf(c1[m][ns][r] + bb, 0.0f));
    }
    __syncthreads();                       // bar2: H visible; XB now dead

    // ---- C3+C4: GRU ns-split; per pass: 12 frag-pairs, depth-4 prefetch ----
    float* XBf = (float*)XB;
    #pragma unroll
    for (int ns = 0; ns < 2; ++ns) {
        f32x4 arz[2][2] = {};   // [m][gate r/z]
        f32x4 an_i[2] = {};
        f32x4 an_h[2] = {};
        const ushort* am = &HB[r16 * XASTR + kb * 8];
        const ushort* ah = &XA[r16 * XASTR + kb * 8];
        bf16x8 pi[4], ph[4];
        #pragma unroll
        for (int q = 0; q < 4; ++q) {
            int kt = q / 3, s = q % 3;
            int fo = (kt * 6 + s * 2 + ns) * 512;
            pi[q] = *(const bf16x8*)(wI + fo);
            ph[q] = *(const bf16x8*)(wH + fo);
        }
        #pragma unroll
        for (int q = 0; q < 12; ++q) {
            int kt = q / 3, s = q % 3;
            bf16x8 M0 = *(const bf16x8*)(am + kt * 32);
            bf16x8 M1 = *(const bf16x8*)(am + 16 * XASTR + kt * 32);
            bf16x8 H0 = *(const bf16x8*)(ah + kt * 32);
            bf16x8 H1 = *(const bf16x8*)(ah + 16 * XASTR + kt * 32);
            bf16x8 Bi = pi[q & 3];
            bf16x8 Bh = ph[q & 3];
            if (s < 2) {
                arz[0][s] = MFMA16(M0, Bi, arz[0][s]);
                arz[0][s] = MFMA16(H0, Bh, arz[0][s]);
                arz[1][s] = MFMA16(M1, Bi, arz[1][s]);
                arz[1][s] = MFMA16(H1, Bh, arz[1][s]);
            } else {
                an_i[0] = MFMA16(M0, Bi, an_i[0]);
                an_i[1] = MFMA16(M1, Bi, an_i[1]);
                an_h[0] = MFMA16(H0, Bh, an_h[0]);
                an_h[1] = MFMA16(H1, Bh, an_h[1]);
            }
            if (q + 4 < 12) {
                int kq = (q + 4) / 3, sq = (q + 4) % 3;
                int fo = (kq * 6 + sq * 2 + ns) * 512;
                pi[q & 3] = *(const bf16x8*)(wI + fo);
                ph[q & 3] = *(const bf16x8*)(wH + fo);
            }
        }
        // C4 for this ns: gates + blend -> f32 stage into XB (dead since bar2)
        {
            int col = wv * 32 + ns * 16 + r16;
            float brz0 = cb[col] + bhh[col];
            float brz1 = cb[128 + col] + bhh[128 + col];
            float bin  = cb[256 + col];
            float bhn  = bhh[256 + col];
            #pragma unroll
            for (int m = 0; m < 2; ++m) {
                #pragma unroll
                for (int r = 0; r < 4; ++r) {
                    int row = m * 16 + kb * 4 + r;
                    float rr = sigm(arz[m][0][r] + brz0);
                    float zz = sigm(arz[m][1][r] + brz1);
                    float nn = tanh_f(an_i[m][r] + bin + rr * (an_h[m][r] + bhn));
                    float hh = b2f(XA[row * XASTR + col]);
                    XBf[row * OSTR + col] = fmaf(zz, hh - nn, nn);   // (1-z)n + zh
                }
            }
        }
    }
    __syncthreads();                       // bar3: out-stage visible

    // ---- C5: coalesced store, present rows only (absent handled in k_pg) ----
    for (int j = wv; j < 32; j += 4) {
        if (pres[j]) {
            float2 v = *(const float2*)&XBf[j * OSTR + lane * 2];
            *(float2*)&out[(size_t)(base + j) * 128 + lane * 2] = v;
        }
    }
}

extern "C" void kernel_launch(void* const* d_in, const int* in_sizes, int n_in,
                              void* d_out, int out_size, void* d_ws, size_t ws_size,
                              hipStream_t stream) {
    const int*   src  = (const int*)d_in[0];
    const int*   dst  = (const int*)d_in[1];
    const float* ef   = (const float*)d_in[2];
    const float* ts   = (const float*)d_in[3];
    const float* mem  = (const float*)d_in[4];
    const float* lut  = (const float*)d_in[5];
    const float* tw   = (const float*)d_in[6];
    const float* tphi = (const float*)d_in[7];
    const float* W1   = (const float*)d_in[8];
    const float* b1   = (const float*)d_in[9];
    const float* W2   = (const float*)d_in[10];
    const float* b2   = (const float*)d_in[11];
    const float* Wih  = (const float*)d_in[12];
    const float* Whh  = (const float*)d_in[13];
    const float* bih  = (const float*)d_in[14];
    const float* bhh  = (const float*)d_in[15];
    float* out = (float*)d_out;

    char* ws = (char*)d_ws;
    size_t off = 0;
    int*    last_pos = (int*)(ws + off);    off += (size_t)NN * 4;
    ushort* W1F      = (ushort*)(ws + off); off += (size_t)104 * 512 * 2;
    ushort* W2IF     = (ushort*)(ws + off); off += (size_t)96 * 512 * 2;
    ushort* WHF      = (ushort*)(ws + off); off += (size_t)96 * 512 * 2;
    float*  cb       = (float*)(ws + off);  off += (size_t)384 * 4 + 64;
    ushort* PB       = (ushort*)(ws + off);   // NN * XBSTR * 2 = 118.4 MB

    hipMemsetAsync(last_pos, 0xFF, (size_t)NN * sizeof(int), stream);  // -1

    k_scatter<<<(2 * NE + 255) / 256, 256, 0, stream>>>(src, dst, last_pos);
    k_pg<<<NB_PREP + NB_GATH, 256, 0, stream>>>(
        W1, W2, Wih, Whh, b2, bih, W1F, W2IF, WHF, cb,
        last_pos, src, dst, ts, lut, mem, ef, tw, tphi, PB, out);
    k_main10<<<NT, 256, 0, stream>>>(PB, last_pos, mem, W1F, b1, W2IF, WHF, cb, bhh, out);
}